// Round 10
// baseline (182.277 us; speedup 1.0000x reference)
//
#include <hip/hip_runtime.h>
#include <math.h>

namespace {
constexpr int kB = 4;
constexpr int kS = 4096;
constexpr int kD = 1024;
constexpr int kM = 128;
constexpr int kC = 64;           // chunk length
constexpr int kNC = kS / kC;     // 64 chunks per batch
constexpr int kNCG = kB * kNC;   // 256 global chunks
constexpr int kRS = kB * kS;     // 16384 rows
constexpr float kLR = 0.01f;
constexpr float kLog2d = -0.0144995696f;   // log2(0.99)
}

typedef __bf16 bf16x8 __attribute__((ext_vector_type(8)));
typedef float  f32x4  __attribute__((ext_vector_type(4)));
typedef unsigned short u16;
typedef unsigned int   u32;

__device__ __forceinline__ u16 f2bf(float f) {
  u32 x = __float_as_uint(f);
  u32 r = (x + 0x7fffu + ((x >> 16) & 1u)) >> 16;   // RNE
  return (u16)r;
}

__device__ __forceinline__ float bf2f(u16 h) {
  return __uint_as_float(((u32)h) << 16);
}

__device__ __forceinline__ void gl_lds16(const void* g, void* l) {
  __builtin_amdgcn_global_load_lds(
      (const __attribute__((address_space(1))) void*)g,
      (__attribute__((address_space(3))) void*)l, 16, 0, 0);
}

__device__ __forceinline__ f32x4 mf(bf16x8 a, bf16x8 b, f32x4 c) {
  return __builtin_amdgcn_mfma_f32_16x16x32_bf16(a, b, c, 0, 0, 0);
}

__device__ __forceinline__ ushort4 pack4(float4 a) {
  ushort4 o;
  o.x = f2bf(a.x); o.y = f2bf(a.y); o.z = f2bf(a.z); o.w = f2bf(a.w);
  return o;
}

// Fragment-panel layouts: 1 KiB panel = 16 rows x 32 cols bf16; element (r,c)
// at byte ((c>>3)&3)*256 + (r&15)*16 + (c&7)*2 within panel. A wave
// ds_read_b128 of one fragment (lane -> qd*256 + fr*16) is a contiguous 1 KiB.
__device__ __forceinline__ int fo64x128(int r, int c) {   // rows<=64 x 128 cols
  return ((r >> 4) * 4 + (c >> 5)) * 1024 + ((c >> 3) & 3) * 256 + (r & 15) * 16 + (c & 7) * 2;
}
__device__ __forceinline__ int fo128x64(int r, int c) {   // 128 rows x 64 cols
  return ((r >> 4) * 2 + (c >> 5)) * 1024 + ((c >> 3) & 3) * 256 + (r & 15) * 16 + (c & 7) * 2;
}
__device__ __forceinline__ int fo64x64(int r, int c) {    // 64 rows x 64 cols
  return ((r >> 4) * 2 + (c >> 5)) * 1024 + ((c >> 3) & 3) * 256 + (r & 15) * 16 + (c & 7) * 2;
}

// ---------------------------------------------------------------------------
// cast: Wk|Wv|Wq -> Wkvqf PRE-FRAGMENTED bf16; Wo -> Wohf PRE-FRAGMENTED bf16.
// Wkvqf fragment (slab s, n-panel p(0..7), K-step32 st(0..31)):
//   base u16 = ((s*8+p)*32 + st)*512, lane layout qd*128 + fr*8 + e.
// ---------------------------------------------------------------------------
__global__ __launch_bounds__(256)
void cast_w_kernel(const float* __restrict__ Wk, const float* __restrict__ Wv,
                   const float* __restrict__ Wq, const float* __restrict__ Wo,
                   u16* __restrict__ Wkvqf, u16* __restrict__ Wohf)
{
  int i = (blockIdx.x * 256 + threadIdx.x) * 4;   // < 524288
  if (i < 393216) {
    const float* src = (i < 131072) ? Wk + i
                     : (i < 262144) ? Wv + (i - 131072) : Wq + (i - 262144);
    float4 v = *(const float4*)src;
    const int n = i >> 10, c = i & 1023;
    const int s = n >> 7, p = (n >> 4) & 7, fr = n & 15;
    const int st = c >> 5, qd = (c >> 3) & 3, e = c & 7;
    u16* dst = Wkvqf + ((size_t)((s * 8 + p) * 32 + st) * 512
                        + qd * 128 + fr * 8 + e);
    *(ushort4*)dst = pack4(v);
  } else {
    const int widx = i - 393216;       // element in Wo [1024][128]
    float4 v = *(const float4*)(Wo + widx);
    const int d = widx >> 7, m = widx & 127;
    u16* dst = Wohf + ((size_t)((d >> 4) * 4 + (m >> 5)) * 512
                       + ((m >> 3) & 3) * 128 + (d & 15) * 8 + (m & 7));
    *(ushort4*)dst = pack4(v);
  }
}

// ---------------------------------------------------------------------------
// proj_gemm v10: tile 64 x 128, BK=32 -> LDS 24 KiB -> 6 blocks/CU.
// Grid (256 chunks, 3 slabs), 256 threads. Same staged bytes / MFMA count as
// BK=64; 32 thinner double-buffered steps. Single-register-set A prefetch
// (xv holds x(i+1) at step i — the scheme round-5 proved correct).
// ---------------------------------------------------------------------------
__global__ __launch_bounds__(256, 6)
void proj_gemm(const float* __restrict__ x, const u16* __restrict__ Wkvqf,
               const float* __restrict__ bk, const float* __restrict__ bv,
               const float* __restrict__ bq,
               u16* __restrict__ Qg, u16* __restrict__ Kg,
               u16* __restrict__ VTg, u16* __restrict__ KwTg)
{
  __shared__ __align__(16) u16 L[12288];   // 24 KiB
  const int cg = blockIdx.x, s = blockIdx.y;
  const int R0 = cg * 64;
  const int tid = threadIdx.x, w = tid >> 6, lane = tid & 63;
  const int fr = lane & 15, qd = lane >> 4;
  const int wr = w >> 1, wc = w & 1;

  constexpr int A0 = 0, A1o = 4096, B0 = 8192, B1o = 16384;   // byte offsets

  // A staging: thread -> row xr (0..63), col-group s4 (8 cols of 32)
  const int xr = tid >> 2, s4 = tid & 3;
  const float* xp = x + (size_t)(R0 + xr) * kD + s4 * 8;
  const int aoff = (xr >> 4) * 1024 + s4 * 256 + (xr & 15) * 16;  // byte in A buf

  const u16* wbase = Wkvqf + (size_t)s * 131072 + lane * 8;

  f32x4 acc[2][4] = {};
  float4 xa, xb;   // single set: holds x(i+1) at start of step i

  auto stageB = [&](int st, int buf) {
#pragma unroll
    for (int g = 0; g < 2; ++g) {
      const int pn = 2 * w + g;
      gl_lds16(wbase + (size_t)(pn * 32 + st) * 512, &L[(buf + pn * 1024) >> 1]);
    }
  };
  auto writeA = [&](int buf) {
    union { ushort4 h[2]; uint4 u; } r;
    r.h[0] = pack4(xa); r.h[1] = pack4(xb);
    *(uint4*)&L[(buf + aoff) >> 1] = r.u;
  };
  auto loadX = [&](int t) {
    xa = *(const float4*)(xp + t * 32);
    xb = *(const float4*)(xp + t * 32 + 4);
  };
  auto compute = [&](int Abuf, int Bbuf) {
    bf16x8 af[2], bf4[4];
#pragma unroll
    for (int mi = 0; mi < 2; ++mi)
      af[mi] = *(const bf16x8*)&L[(Abuf + (wr * 2 + mi) * 1024 + qd * 256 + fr * 16) >> 1];
#pragma unroll
    for (int ng = 0; ng < 4; ++ng)
      bf4[ng] = *(const bf16x8*)&L[(Bbuf + (wc * 4 + ng) * 1024 + qd * 256 + fr * 16) >> 1];
#pragma unroll
    for (int mi = 0; mi < 2; ++mi)
#pragma unroll
      for (int ng = 0; ng < 4; ++ng)
        acc[mi][ng] = mf(af[mi], bf4[ng], acc[mi][ng]);
  };

  // prologue: stage step 0; write x(0); load x(1)
  stageB(0, B0);
  loadX(0); writeA(A0);
  loadX(1);
  __syncthreads();

#pragma unroll 2
  for (int i = 0; i < 32; ++i) {
    const int Ac = (i & 1) ? A1o : A0, Bc = (i & 1) ? B1o : B0;
    const int An = (i & 1) ? A0 : A1o, Bn = (i & 1) ? B0 : B1o;
    if (i < 31) {
      stageB(i + 1, Bn);
      writeA(An);              // xv = x(i+1)
      if (i < 30) loadX(i + 2);
    }
    compute(Ac, Bc);
    __syncthreads();
  }

  // epilogue: bias + per-slab fragment-layout stores
  // coords: t = wr*32 + mi*16 + qd*4 + r ; n = wc*64 + ng*16 + fr
  const float* bp = (s == 0) ? bk : (s == 1) ? bv : bq;
  float bias[4];
#pragma unroll
  for (int ng = 0; ng < 4; ++ng) bias[ng] = bp[wc * 64 + ng * 16 + fr];
  const size_t cb = (size_t)cg * 8192;

  if (s == 0) {
    float dp[2][4];
#pragma unroll
    for (int mi = 0; mi < 2; ++mi)
#pragma unroll
      for (int r = 0; r < 4; ++r)
        dp[mi][r] = kLR * exp2f((float)(63 - (wr * 32 + mi * 16 + qd * 4 + r)) * kLog2d);
#pragma unroll
    for (int mi = 0; mi < 2; ++mi)
#pragma unroll
      for (int ng = 0; ng < 4; ++ng)
#pragma unroll
        for (int r = 0; r < 4; ++r) {
          const int t = wr * 32 + mi * 16 + qd * 4 + r, n = wc * 64 + ng * 16 + fr;
          const float v = acc[mi][ng][r] + bias[ng];
          Kg[cb + (fo64x128(t, n) >> 1)] = f2bf(v);
          KwTg[cb + (fo128x64(n, t) >> 1)] = f2bf(v * dp[mi][r]);
        }
  } else if (s == 1) {
#pragma unroll
    for (int mi = 0; mi < 2; ++mi)
#pragma unroll
      for (int ng = 0; ng < 4; ++ng)
#pragma unroll
        for (int r = 0; r < 4; ++r) {
          const int t = wr * 32 + mi * 16 + qd * 4 + r, n = wc * 64 + ng * 16 + fr;
          VTg[cb + (fo128x64(n, t) >> 1)] = f2bf(acc[mi][ng][r] + bias[ng]);
        }
  } else {
#pragma unroll
    for (int mi = 0; mi < 2; ++mi)
#pragma unroll
      for (int ng = 0; ng < 4; ++ng)
#pragma unroll
        for (int r = 0; r < 4; ++r) {
          const int t = wr * 32 + mi * 16 + qd * 4 + r, n = wc * 64 + ng * 16 + fr;
          Qg[cb + (fo64x128(t, n) >> 1)] = f2bf(acc[mi][ng][r] + bias[ng]);
        }
  }
}

// ---------------------------------------------------------------------------
// intra_kernel (round-5 measured best): per (chunk, i-half): P = Q K^T
// (duplicated per half), At = mask/decay(P), O1 = At V^T, U = V^T KwT.
// Grid (256,2), 256 threads, 56 KiB LDS: Q@0 K@16K VT-half@32K KwT@40K.
// ---------------------------------------------------------------------------
__global__ __launch_bounds__(256, 2)
void intra_kernel(const u16* __restrict__ Qg, const u16* __restrict__ Kg,
                  const u16* __restrict__ VTg, const u16* __restrict__ KwTg,
                  u16* __restrict__ O1g, float* __restrict__ SU)
{
  __shared__ __align__(16) u16 L[28672];   // 56 KiB
  const int cg = blockIdx.x, ih = blockIdx.y;
  const int tid = threadIdx.x, w = tid >> 6, lane = tid & 63;
  const int fr = lane & 15, qd = lane >> 4;
  const size_t cb = (size_t)cg * 8192;

#pragma unroll
  for (int g = 0; g < 4; ++g) {
    const int pn = 4 * w + g;
    gl_lds16(Qg + cb + pn * 512 + lane * 8, &L[(0 + pn * 1024) >> 1]);
    gl_lds16(Kg + cb + pn * 512 + lane * 8, &L[(16384 + pn * 1024) >> 1]);
    gl_lds16(KwTg + cb + pn * 512 + lane * 8, &L[(40960 + pn * 1024) >> 1]);
  }
#pragma unroll
  for (int g = 0; g < 2; ++g) {
    const int p2 = 2 * w + g;   // 0..7 local V^T panels of this i-half
    gl_lds16(VTg + cb + ih * 4096 + p2 * 512 + lane * 8, &L[(32768 + p2 * 1024) >> 1]);
  }
  __syncthreads();

  // P (full 64x64): wave w = t-frag w
  f32x4 p[4] = {};
#pragma unroll
  for (int kc = 0; kc < 4; ++kc) {
    bf16x8 aq = *(const bf16x8*)&L[(0 + (w * 4 + kc) * 1024 + qd * 256 + fr * 16) >> 1];
#pragma unroll
    for (int ug = 0; ug < 4; ++ug) {
      bf16x8 bkf = *(const bf16x8*)&L[(16384 + (ug * 4 + kc) * 1024 + qd * 256 + fr * 16) >> 1];
      p[ug] = mf(aq, bkf, p[ug]);
    }
  }
  __syncthreads();   // K reads done; reuse K region for At

  // At = mask/decay(P) -> K region, fo64x64
#pragma unroll
  for (int ug = 0; ug < 4; ++ug)
#pragma unroll
    for (int r = 0; r < 4; ++r) {
      const int t = w * 16 + qd * 4 + r, u = ug * 16 + fr;
      float av = 0.f;
      if (u < t) av = kLR * exp2f((float)(t - 1 - u) * kLog2d) * p[ug][r];
      L[(16384 + fo64x64(t, u)) >> 1] = f2bf(av);
    }
  __syncthreads();

  // O1: wave w -> t-frag w x this i-half (4 frags); U: i-row-frag w of half
  f32x4 o1[4] = {}, uu[8] = {};
#pragma unroll
  for (int kc = 0; kc < 2; ++kc) {
    bf16x8 aA = *(const bf16x8*)&L[(16384 + (w * 2 + kc) * 1024 + qd * 256 + fr * 16) >> 1];
    bf16x8 aV = *(const bf16x8*)&L[(32768 + (w * 2 + kc) * 1024 + qd * 256 + fr * 16) >> 1];
#pragma unroll
    for (int ni = 0; ni < 4; ++ni) {
      bf16x8 bV = *(const bf16x8*)&L[(32768 + (ni * 2 + kc) * 1024 + qd * 256 + fr * 16) >> 1];
      o1[ni] = mf(aA, bV, o1[ni]);
    }
#pragma unroll
    for (int jf = 0; jf < 8; ++jf) {
      bf16x8 bK = *(const bf16x8*)&L[(40960 + (jf * 2 + kc) * 1024 + qd * 256 + fr * 16) >> 1];
      uu[jf] = mf(aV, bK, uu[jf]);
    }
  }

  // stores
#pragma unroll
  for (int ni = 0; ni < 4; ++ni)
#pragma unroll
    for (int r = 0; r < 4; ++r) {
      const int t = w * 16 + qd * 4 + r, i2 = (ih * 4 + ni) * 16 + fr;
      O1g[cb + (fo64x128(t, i2) >> 1)] = f2bf(o1[ni][r]);
    }
  float* SUc = SU + (size_t)cg * 16384;
#pragma unroll
  for (int jf = 0; jf < 8; ++jf)
#pragma unroll
    for (int r = 0; r < 4; ++r) {
      const int i2 = ih * 64 + w * 16 + qd * 4 + r, j = jf * 16 + fr;
      SUc[i2 * kM + j] = uu[jf][r];
    }
}

// ---------------------------------------------------------------------------
// inter-chunk scan: Sb16[c] = bf16(state before chunk c); carry -> state_out
// ---------------------------------------------------------------------------
__global__ __launch_bounds__(128)
void scan_kernel(const float* __restrict__ SU, u16* __restrict__ Sb16,
                 float* __restrict__ state_out)
{
  const int e = blockIdx.x * 128 + threadIdx.x;   // < kB * 16384
  const int b = e >> 14, ij = e & 16383;
  const float* base = SU + (size_t)b * kNC * 16384 + ij;
  u16* sb = Sb16 + (size_t)b * kNC * 16384 + ij;
  const float dC = exp2f((float)kC * kLog2d);
  float prev = 0.f;
#pragma unroll 16
  for (int c2 = 0; c2 < kNC; ++c2) {
    const float u = base[(size_t)c2 * 16384];
    sb[(size_t)c2 * 16384] = f2bf(prev);
    prev = fmaf(dC, prev, u);
  }
  state_out[e] = prev;
}

// ---------------------------------------------------------------------------
// fco (round-5 measured best): per (chunk, t-half): O2 = Q S^T;
// Out = bf16(O1 + d^t O2) -> LDS; y = Out @ Woh^T + bo.
// Grid (256,2), 256 threads, 48 KiB LDS: Qhalf@0 (8K, Out reuses),
// S@8K (32K), O1half@40K (8K).
// ---------------------------------------------------------------------------
__global__ __launch_bounds__(256, 2)
void fco(const u16* __restrict__ Qg, const u16* __restrict__ Sb16,
         const u16* __restrict__ O1g, const u16* __restrict__ Wohf,
         const float* __restrict__ bo, float* __restrict__ y)
{
  __shared__ __align__(16) u16 L[24576];   // 48 KiB
  const int cg = blockIdx.x, th = blockIdx.y;
  const int tid = threadIdx.x, w = tid >> 6, lane = tid & 63;
  const int fr = lane & 15, qd = lane >> 4;
  const size_t cb = (size_t)cg * 8192;
  const u16* Sbc = Sb16 + (size_t)cg * 16384;

  // stage Q half + O1 half (contiguous frag panels th*8..th*8+7), S full
#pragma unroll
  for (int g = 0; g < 2; ++g) {
    const int p = 2 * w + g;
    gl_lds16(Qg + cb + (th * 8 + p) * 512 + lane * 8, &L[(0 + p * 1024) >> 1]);
    gl_lds16(O1g + cb + (th * 8 + p) * 512 + lane * 8, &L[(40960 + p * 1024) >> 1]);
  }
#pragma unroll
  for (int g = 0; g < 8; ++g) {
    const int pn = 8 * w + g, ig = pn >> 2, kc = pn & 3;
    gl_lds16(Sbc + (size_t)(ig * 16 + fr) * kM + kc * 32 + qd * 8,
             &L[(8192 + pn * 1024) >> 1]);
  }
  __syncthreads();

  // O2 = Q S^T: wave (tf2 = w>>1, i-half ihl = w&1): 16 t-rows x 64 i
  const int tf2 = w >> 1, ihl = w & 1;
  f32x4 o2[4] = {};
#pragma unroll
  for (int kc = 0; kc < 4; ++kc) {
    bf16x8 aq = *(const bf16x8*)&L[(0 + (tf2 * 4 + kc) * 1024 + qd * 256 + fr * 16) >> 1];
#pragma unroll
    for (int ni = 0; ni < 4; ++ni) {
      bf16x8 bS = *(const bf16x8*)&L[(8192 + ((ihl * 4 + ni) * 4 + kc) * 1024 + qd * 256 + fr * 16) >> 1];
      o2[ni] = mf(aq, bS, o2[ni]);
    }
  }
  __syncthreads();   // Q reads done; Out overwrites Q region

  // Out = bf16(O1 + d^t O2)
#pragma unroll
  for (int ni = 0; ni < 4; ++ni)
#pragma unroll
    for (int r = 0; r < 4; ++r) {
      const int tl = tf2 * 16 + qd * 4 + r;
      const int tg = th * 32 + tl;
      const int i2 = (ihl * 4 + ni) * 16 + fr;
      const float o1v = bf2f(L[(40960 + fo64x128(tl, i2)) >> 1]);
      L[(0 + fo64x128(tl, i2)) >> 1] =
          f2bf(fmaf(exp2f((float)tg * kLog2d), o2[ni][r], o1v));
    }
  __syncthreads();

  // y = Out @ Woh^T + bo; wave w covers d in [256w, 256w+256), 2 halves
  const int R0 = cg * 64 + th * 32;
#pragma unroll 1
  for (int h = 0; h < 2; ++h) {
    const int n0 = w * 256 + h * 128;
    f32x4 fy[2][8] = {};
#pragma unroll
    for (int kc = 0; kc < 4; ++kc) {
      bf16x8 ao[2], bw[8];
#pragma unroll
      for (int mi = 0; mi < 2; ++mi)
        ao[mi] = *(const bf16x8*)&L[((mi * 4 + kc) * 1024 + qd * 256 + fr * 16) >> 1];
#pragma unroll
      for (int nj = 0; nj < 8; ++nj)
        bw[nj] = *(const bf16x8*)&Wohf[((size_t)(w * 16 + h * 8 + nj) * 4 + kc) * 512 + lane * 8];
#pragma unroll
      for (int mi = 0; mi < 2; ++mi)
#pragma unroll
        for (int nj = 0; nj < 8; ++nj)
          fy[mi][nj] = mf(ao[mi], bw[nj], fy[mi][nj]);
    }
#pragma unroll
    for (int nj = 0; nj < 8; ++nj) {
      const int d = n0 + nj * 16 + fr;
      const float bb = bo[d];
#pragma unroll
      for (int mi = 0; mi < 2; ++mi)
#pragma unroll
        for (int r = 0; r < 4; ++r)
          y[(size_t)(R0 + mi * 16 + qd * 4 + r) * kD + d] = fy[mi][nj][r] + bb;
    }
  }
}

// ---------------------------------------------------------------------------
extern "C" void kernel_launch(void* const* d_in, const int* in_sizes, int n_in,
                              void* d_out, int out_size, void* d_ws, size_t ws_size,
                              hipStream_t stream) {
  const float* x  = (const float*)d_in[0];
  const float* Wk = (const float*)d_in[1];
  const float* bk = (const float*)d_in[2];
  const float* Wv = (const float*)d_in[3];
  const float* bv = (const float*)d_in[4];
  const float* Wq = (const float*)d_in[5];
  const float* bq = (const float*)d_in[6];
  const float* Wo = (const float*)d_in[7];
  const float* bo = (const float*)d_in[8];

  char* wsp = (char*)d_ws;
  u16* Wkvqf = (u16*)wsp; wsp += (size_t)384 * 1024 * 2;
  u16* Wohf  = (u16*)wsp; wsp += (size_t)1024 * 128 * 2;
  u16* Qg    = (u16*)wsp; wsp += (size_t)kNCG * 8192 * 2;           // 4 MB
  u16* Kg    = (u16*)wsp; wsp += (size_t)kNCG * 8192 * 2;           // 4 MB
  u16* VTg   = (u16*)wsp;
  u16* KwTg  = VTg + (size_t)kNCG * 8192;
  u16* Sb16  = VTg;                                                  // alias: VTg/KwTg dead after intra
  wsp += (size_t)kNCG * 16384 * 2;                                   // 8 MB
  u16* O1g   = (u16*)wsp; wsp += (size_t)kNCG * 8192 * 2;           // 4 MB
  float* SU  = (float*)wsp; wsp += (size_t)kNCG * 16384 * 4;        // 16 MB

  float* y = (float*)d_out;
  float* state_out = y + (size_t)kRS * kD;

  cast_w_kernel<<<dim3(512), dim3(256), 0, stream>>>(Wk, Wv, Wq, Wo, Wkvqf, Wohf);
  proj_gemm<<<dim3(kNCG, 3), dim3(256), 0, stream>>>(x, Wkvqf, bk, bv, bq, Qg, Kg, VTg, KwTg);
  intra_kernel<<<dim3(kNCG, 2), dim3(256), 0, stream>>>(Qg, Kg, VTg, KwTg, O1g, SU);
  scan_kernel<<<dim3(kB * 16384 / 128), dim3(128), 0, stream>>>(SU, Sb16, state_out);
  fco<<<dim3(kNCG, 2), dim3(256), 0, stream>>>(Qg, Sb16, O1g, Wohf, bo, y);
}

// Round 11
// 174.141 us; speedup vs baseline: 1.0467x; 1.0467x over previous
//
#include <hip/hip_runtime.h>
#include <math.h>

namespace {
constexpr int kB = 4;
constexpr int kS = 4096;
constexpr int kD = 1024;
constexpr int kM = 128;
constexpr int kC = 64;           // chunk length
constexpr int kNC = kS / kC;     // 64 chunks per batch
constexpr int kNCG = kB * kNC;   // 256 global chunks
constexpr int kRS = kB * kS;     // 16384 rows
constexpr float kLR = 0.01f;
constexpr float kLog2d = -0.0144995696f;   // log2(0.99)
}

typedef __bf16 bf16x8 __attribute__((ext_vector_type(8)));
typedef float  f32x4  __attribute__((ext_vector_type(4)));
typedef unsigned short u16;
typedef unsigned int   u32;

__device__ __forceinline__ u16 f2bf(float f) {
  u32 x = __float_as_uint(f);
  u32 r = (x + 0x7fffu + ((x >> 16) & 1u)) >> 16;   // RNE
  return (u16)r;
}

__device__ __forceinline__ float bf2f(u16 h) {
  return __uint_as_float(((u32)h) << 16);
}

__device__ __forceinline__ void gl_lds16(const void* g, void* l) {
  __builtin_amdgcn_global_load_lds(
      (const __attribute__((address_space(1))) void*)g,
      (__attribute__((address_space(3))) void*)l, 16, 0, 0);
}

__device__ __forceinline__ f32x4 mf(bf16x8 a, bf16x8 b, f32x4 c) {
  return __builtin_amdgcn_mfma_f32_16x16x32_bf16(a, b, c, 0, 0, 0);
}

__device__ __forceinline__ ushort4 pack4(float4 a) {
  ushort4 o;
  o.x = f2bf(a.x); o.y = f2bf(a.y); o.z = f2bf(a.z); o.w = f2bf(a.w);
  return o;
}

// Fragment-panel layouts: 1 KiB panel = 16 rows x 32 cols bf16; element (r,c)
// at byte ((c>>3)&3)*256 + (r&15)*16 + (c&7)*2 within panel. A wave
// ds_read_b128 of one fragment (lane -> qd*256 + fr*16) is a contiguous 1 KiB.
__device__ __forceinline__ int fo64x128(int r, int c) {   // rows<=64 x 128 cols
  return ((r >> 4) * 4 + (c >> 5)) * 1024 + ((c >> 3) & 3) * 256 + (r & 15) * 16 + (c & 7) * 2;
}
__device__ __forceinline__ int fo128x64(int r, int c) {   // 128 rows x 64 cols
  return ((r >> 4) * 2 + (c >> 5)) * 1024 + ((c >> 3) & 3) * 256 + (r & 15) * 16 + (c & 7) * 2;
}
__device__ __forceinline__ int fo64x64(int r, int c) {    // 64 rows x 64 cols
  return ((r >> 4) * 2 + (c >> 5)) * 1024 + ((c >> 3) & 3) * 256 + (r & 15) * 16 + (c & 7) * 2;
}

// ---------------------------------------------------------------------------
// cast: Wk|Wv|Wq -> Wkvqf PRE-FRAGMENTED bf16; Wo -> Wohf PRE-FRAGMENTED bf16.
// Wkvqf u16 offset(n,k): s=n>>7,p=(n>>4)&7,fr=n&15,t=k>>6,kh=(k>>5)&1,
//   qd=(k>>3)&3,e=k&7 -> ((s*8+p)*32 + t*2+kh)*512 + qd*128 + fr*8 + e.
// Wohf u16 offset(d,m): ((d>>4)*4 + (m>>5))*512 + ((m>>3)&3)*128 + (d&15)*8 + (m&7).
// Every consumer wave-load of a fragment is then a contiguous 1 KiB.
// ---------------------------------------------------------------------------
__global__ __launch_bounds__(256)
void cast_w_kernel(const float* __restrict__ Wk, const float* __restrict__ Wv,
                   const float* __restrict__ Wq, const float* __restrict__ Wo,
                   u16* __restrict__ Wkvqf, u16* __restrict__ Wohf)
{
  int i = (blockIdx.x * 256 + threadIdx.x) * 4;   // < 524288
  if (i < 393216) {
    const float* src = (i < 131072) ? Wk + i
                     : (i < 262144) ? Wv + (i - 131072) : Wq + (i - 262144);
    float4 v = *(const float4*)src;
    const int n = i >> 10, c = i & 1023;
    const int s = n >> 7, p = (n >> 4) & 7, fr = n & 15;
    const int t = c >> 6, kh = (c >> 5) & 1, qd = (c >> 3) & 3, e = c & 7;
    u16* dst = Wkvqf + ((size_t)((s * 8 + p) * 32 + t * 2 + kh) * 512
                        + qd * 128 + fr * 8 + e);
    *(ushort4*)dst = pack4(v);
  } else {
    const int widx = i - 393216;       // element in Wo [1024][128]
    float4 v = *(const float4*)(Wo + widx);
    const int d = widx >> 7, m = widx & 127;
    u16* dst = Wohf + ((size_t)((d >> 4) * 4 + (m >> 5)) * 512
                       + ((m >> 3) & 3) * 128 + (d & 15) * 8 + (m & 7));
    *(ushort4*)dst = pack4(v);
  }
}

// ---------------------------------------------------------------------------
// proj_gemm: C[16384 x 384] = x @ Wkvq^T (+bias in epilogue), tiled GEMM.
// Measured best (41 us, FETCH 36 MB, 3 blocks/CU): tile 64 rows x 128 cols,
// BK=64, double-buffered, 48 KiB LDS, grid (256 chunks, 3 slabs), 256 thr.
// B staging sources are contiguous 1 KiB (pre-fragmented Wkvqf).
// ---------------------------------------------------------------------------
__global__ __launch_bounds__(256, 3)
void proj_gemm(const float* __restrict__ x, const u16* __restrict__ Wkvqf,
               const float* __restrict__ bk, const float* __restrict__ bv,
               const float* __restrict__ bq,
               u16* __restrict__ Qg, u16* __restrict__ Kg,
               u16* __restrict__ VTg, u16* __restrict__ KwTg)
{
  __shared__ __align__(16) u16 L[24576];   // 48 KiB
  const int cg = blockIdx.x, s = blockIdx.y;
  const int R0 = cg * 64;
  const int tid = threadIdx.x, w = tid >> 6, lane = tid & 63;
  const int fr = lane & 15, qd = lane >> 4;
  const int wr = w >> 1, wc = w & 1;

  constexpr int A0 = 0, A1o = 8192, B0 = 16384, B1o = 32768;   // byte offsets

  // A staging: thread -> row xr, 4 float4 groups at cols s4*4 + 16q
  const int xr = tid >> 2, s4 = tid & 3;
  const float* xp = x + (size_t)(R0 + xr) * kD + s4 * 4;
  int aoffq[4];
#pragma unroll
  for (int q = 0; q < 4; ++q)
    aoffq[q] = ((xr >> 4) * 2 + (q >> 1)) * 1024 + (((s4 >> 1) + 2 * q) & 3) * 256
             + (xr & 15) * 16 + (s4 & 1) * 8;

  // B staging: slab-base of pre-fragmented weights; fragment (p, t, kh) at
  // (p*32 + t*2 + kh)*512 u16, contiguous per wave-load.
  const u16* wbase = Wkvqf + (size_t)s * 131072 + lane * 8;

  f32x4 acc[2][4] = {};
  float4 xv[4];

  // prologue: stage step 0, prefetch x regs for step 1
  {
#pragma unroll
    for (int g = 0; g < 4; ++g) {
      const int pn = 4 * w + g, p = pn >> 1, kh = pn & 1;
      gl_lds16(wbase + (size_t)(p * 32 + kh) * 512, &L[(B0 + pn * 1024) >> 1]);
    }
    float4 x0[4];
#pragma unroll
    for (int q = 0; q < 4; ++q) x0[q] = *(const float4*)(xp + q * 16);
#pragma unroll
    for (int q = 0; q < 4; ++q) *(ushort4*)&L[(A0 + aoffq[q]) >> 1] = pack4(x0[q]);
#pragma unroll
    for (int q = 0; q < 4; ++q) xv[q] = *(const float4*)(xp + 64 + q * 16);
  }
  __syncthreads();

#pragma unroll 2
  for (int i = 0; i < 16; ++i) {
    const int Ac = (i & 1) ? A1o : A0, Bc = (i & 1) ? B1o : B0;
    const int An = (i & 1) ? A0 : A1o, Bn = (i & 1) ? B0 : B1o;
    if (i < 15) {
      const int t1 = i + 1;
#pragma unroll
      for (int g = 0; g < 4; ++g) {
        const int pn = 4 * w + g, p = pn >> 1, kh = pn & 1;
        gl_lds16(wbase + (size_t)(p * 32 + t1 * 2 + kh) * 512, &L[(Bn + pn * 1024) >> 1]);
      }
#pragma unroll
      for (int q = 0; q < 4; ++q) *(ushort4*)&L[(An + aoffq[q]) >> 1] = pack4(xv[q]);
      if (i < 14) {
#pragma unroll
        for (int q = 0; q < 4; ++q) xv[q] = *(const float4*)(xp + (i + 2) * 64 + q * 16);
      }
    }
    bf16x8 af[2][2], bfr[2][4];
#pragma unroll
    for (int kh = 0; kh < 2; ++kh) {
#pragma unroll
      for (int mi = 0; mi < 2; ++mi)
        af[kh][mi] = *(const bf16x8*)&L[(Ac + ((wr * 2 + mi) * 2 + kh) * 1024 + qd * 256 + fr * 16) >> 1];
#pragma unroll
      for (int ng = 0; ng < 4; ++ng)
        bfr[kh][ng] = *(const bf16x8*)&L[(Bc + ((wc * 4 + ng) * 2 + kh) * 1024 + qd * 256 + fr * 16) >> 1];
    }
#pragma unroll
    for (int kh = 0; kh < 2; ++kh)
#pragma unroll
      for (int mi = 0; mi < 2; ++mi)
#pragma unroll
        for (int ng = 0; ng < 4; ++ng)
          acc[mi][ng] = mf(af[kh][mi], bfr[kh][ng], acc[mi][ng]);
    __syncthreads();
  }

  // epilogue: bias + per-slab stores (coords: t = wr*32+mi*16+qd*4+r,
  // n = wc*64+ng*16+fr)
  const float* bp = (s == 0) ? bk : (s == 1) ? bv : bq;
  float bias[4];
#pragma unroll
  for (int ng = 0; ng < 4; ++ng) bias[ng] = bp[wc * 64 + ng * 16 + fr];
  const size_t cb = (size_t)cg * 8192;

  if (s == 0) {
    float dp[2][4];
#pragma unroll
    for (int mi = 0; mi < 2; ++mi)
#pragma unroll
      for (int r = 0; r < 4; ++r)
        dp[mi][r] = kLR * exp2f((float)(63 - (wr * 32 + mi * 16 + qd * 4 + r)) * kLog2d);
#pragma unroll
    for (int mi = 0; mi < 2; ++mi)
#pragma unroll
      for (int ng = 0; ng < 4; ++ng)
#pragma unroll
        for (int r = 0; r < 4; ++r) {
          const int t = wr * 32 + mi * 16 + qd * 4 + r, n = wc * 64 + ng * 16 + fr;
          const float v = acc[mi][ng][r] + bias[ng];
          Kg[cb + (fo64x128(t, n) >> 1)] = f2bf(v);
          KwTg[cb + (fo128x64(n, t) >> 1)] = f2bf(v * dp[mi][r]);
        }
  } else if (s == 1) {
#pragma unroll
    for (int mi = 0; mi < 2; ++mi)
#pragma unroll
      for (int ng = 0; ng < 4; ++ng)
#pragma unroll
        for (int r = 0; r < 4; ++r) {
          const int t = wr * 32 + mi * 16 + qd * 4 + r, n = wc * 64 + ng * 16 + fr;
          VTg[cb + (fo128x64(n, t) >> 1)] = f2bf(acc[mi][ng][r] + bias[ng]);
        }
  } else {
#pragma unroll
    for (int mi = 0; mi < 2; ++mi)
#pragma unroll
      for (int ng = 0; ng < 4; ++ng)
#pragma unroll
        for (int r = 0; r < 4; ++r) {
          const int t = wr * 32 + mi * 16 + qd * 4 + r, n = wc * 64 + ng * 16 + fr;
          Qg[cb + (fo64x128(t, n) >> 1)] = f2bf(acc[mi][ng][r] + bias[ng]);
        }
  }
}

// ---------------------------------------------------------------------------
// intra_kernel: per (chunk, i-half): P = Q K^T (full, duplicated per half),
// At = mask/decay(P), O1[t][i-half] = At V^T, U[i-half][j] = V^T KwT.
// Grid (256,2), 256 threads, 56 KiB LDS:
// Q@0(16K) K@16K(16K) VThalf@32K(8K) KwT@40K(16K); At overwrites K after P.
// ---------------------------------------------------------------------------
__global__ __launch_bounds__(256, 2)
void intra_kernel(const u16* __restrict__ Qg, const u16* __restrict__ Kg,
                  const u16* __restrict__ VTg, const u16* __restrict__ KwTg,
                  u16* __restrict__ O1g, float* __restrict__ SU)
{
  __shared__ __align__(16) u16 L[28672];   // 56 KiB
  const int cg = blockIdx.x, ih = blockIdx.y;
  const int tid = threadIdx.x, w = tid >> 6, lane = tid & 63;
  const int fr = lane & 15, qd = lane >> 4;
  const size_t cb = (size_t)cg * 8192;

#pragma unroll
  for (int g = 0; g < 4; ++g) {
    const int pn = 4 * w + g;
    gl_lds16(Qg + cb + pn * 512 + lane * 8, &L[(0 + pn * 1024) >> 1]);
    gl_lds16(Kg + cb + pn * 512 + lane * 8, &L[(16384 + pn * 1024) >> 1]);
    gl_lds16(KwTg + cb + pn * 512 + lane * 8, &L[(40960 + pn * 1024) >> 1]);
  }
#pragma unroll
  for (int g = 0; g < 2; ++g) {
    const int p2 = 2 * w + g;   // 0..7 local V^T panels of this i-half
    gl_lds16(VTg + cb + ih * 4096 + p2 * 512 + lane * 8, &L[(32768 + p2 * 1024) >> 1]);
  }
  __syncthreads();

  // P (full 64x64): wave w = t-frag w
  f32x4 p[4] = {};
#pragma unroll
  for (int kc = 0; kc < 4; ++kc) {
    bf16x8 aq = *(const bf16x8*)&L[(0 + (w * 4 + kc) * 1024 + qd * 256 + fr * 16) >> 1];
#pragma unroll
    for (int ug = 0; ug < 4; ++ug) {
      bf16x8 bkf = *(const bf16x8*)&L[(16384 + (ug * 4 + kc) * 1024 + qd * 256 + fr * 16) >> 1];
      p[ug] = mf(aq, bkf, p[ug]);
    }
  }
  __syncthreads();   // K reads done; reuse K region for At

  // At = mask/decay(P) -> K region, fo64x64
#pragma unroll
  for (int ug = 0; ug < 4; ++ug)
#pragma unroll
    for (int r = 0; r < 4; ++r) {
      const int t = w * 16 + qd * 4 + r, u = ug * 16 + fr;
      float av = 0.f;
      if (u < t) av = kLR * exp2f((float)(t - 1 - u) * kLog2d) * p[ug][r];
      L[(16384 + fo64x64(t, u)) >> 1] = f2bf(av);
    }
  __syncthreads();

  // O1: wave w -> t-frag w x this i-half (4 frags); U: i-row-frag w of half
  f32x4 o1[4] = {}, uu[8] = {};
#pragma unroll
  for (int kc = 0; kc < 2; ++kc) {
    bf16x8 aA = *(const bf16x8*)&L[(16384 + (w * 2 + kc) * 1024 + qd * 256 + fr * 16) >> 1];
    bf16x8 aV = *(const bf16x8*)&L[(32768 + (w * 2 + kc) * 1024 + qd * 256 + fr * 16) >> 1];
#pragma unroll
    for (int ni = 0; ni < 4; ++ni) {
      bf16x8 bV = *(const bf16x8*)&L[(32768 + (ni * 2 + kc) * 1024 + qd * 256 + fr * 16) >> 1];
      o1[ni] = mf(aA, bV, o1[ni]);
    }
#pragma unroll
    for (int jf = 0; jf < 8; ++jf) {
      bf16x8 bK = *(const bf16x8*)&L[(40960 + (jf * 2 + kc) * 1024 + qd * 256 + fr * 16) >> 1];
      uu[jf] = mf(aV, bK, uu[jf]);
    }
  }

  // stores
#pragma unroll
  for (int ni = 0; ni < 4; ++ni)
#pragma unroll
    for (int r = 0; r < 4; ++r) {
      const int t = w * 16 + qd * 4 + r, i2 = (ih * 4 + ni) * 16 + fr;
      O1g[cb + (fo64x128(t, i2) >> 1)] = f2bf(o1[ni][r]);
    }
  float* SUc = SU + (size_t)cg * 16384;
#pragma unroll
  for (int jf = 0; jf < 8; ++jf)
#pragma unroll
    for (int r = 0; r < 4; ++r) {
      const int i2 = ih * 64 + w * 16 + qd * 4 + r, j = jf * 16 + fr;
      SUc[i2 * kM + j] = uu[jf][r];
    }
}

// ---------------------------------------------------------------------------
// inter-chunk scan: Sb16[c] = bf16(state before chunk c); carry -> state_out
// 512 blocks x 128 threads, unroll 16.
// ---------------------------------------------------------------------------
__global__ __launch_bounds__(128)
void scan_kernel(const float* __restrict__ SU, u16* __restrict__ Sb16,
                 float* __restrict__ state_out)
{
  const int e = blockIdx.x * 128 + threadIdx.x;   // < kB * 16384
  const int b = e >> 14, ij = e & 16383;
  const float* base = SU + (size_t)b * kNC * 16384 + ij;
  u16* sb = Sb16 + (size_t)b * kNC * 16384 + ij;
  const float dC = exp2f((float)kC * kLog2d);
  float prev = 0.f;
#pragma unroll 16
  for (int c2 = 0; c2 < kNC; ++c2) {
    const float u = base[(size_t)c2 * 16384];
    sb[(size_t)c2 * 16384] = f2bf(prev);
    prev = fmaf(dC, prev, u);
  }
  state_out[e] = prev;
}

// ---------------------------------------------------------------------------
// fco: per (chunk, t-half): O2 = Q S^T; Out = bf16(O1 + d^t O2) -> LDS;
// y = Out @ Woh^T + bo (Wohf pre-fragmented: contiguous 1 KiB B reads).
// Grid (256,2), 256 threads, 48 KiB LDS:
// Qhalf@0 (8K, Out reuses), S@8K (32K), O1half@40K (8K).
// ---------------------------------------------------------------------------
__global__ __launch_bounds__(256, 2)
void fco(const u16* __restrict__ Qg, const u16* __restrict__ Sb16,
         const u16* __restrict__ O1g, const u16* __restrict__ Wohf,
         const float* __restrict__ bo, float* __restrict__ y)
{
  __shared__ __align__(16) u16 L[24576];   // 48 KiB
  const int cg = blockIdx.x, th = blockIdx.y;
  const int tid = threadIdx.x, w = tid >> 6, lane = tid & 63;
  const int fr = lane & 15, qd = lane >> 4;
  const size_t cb = (size_t)cg * 8192;
  const u16* Sbc = Sb16 + (size_t)cg * 16384;

  // stage Q half + O1 half (contiguous frag panels th*8..th*8+7), S full
#pragma unroll
  for (int g = 0; g < 2; ++g) {
    const int p = 2 * w + g;
    gl_lds16(Qg + cb + (th * 8 + p) * 512 + lane * 8, &L[(0 + p * 1024) >> 1]);
    gl_lds16(O1g + cb + (th * 8 + p) * 512 + lane * 8, &L[(40960 + p * 1024) >> 1]);
  }
#pragma unroll
  for (int g = 0; g < 8; ++g) {
    const int pn = 8 * w + g, ig = pn >> 2, kc = pn & 3;
    gl_lds16(Sbc + (size_t)(ig * 16 + fr) * kM + kc * 32 + qd * 8,
             &L[(8192 + pn * 1024) >> 1]);
  }
  __syncthreads();

  // O2 = Q S^T: wave (tf2 = w>>1, i-half ihl = w&1): 16 t-rows x 64 i
  const int tf2 = w >> 1, ihl = w & 1;
  f32x4 o2[4] = {};
#pragma unroll
  for (int kc = 0; kc < 4; ++kc) {
    bf16x8 aq = *(const bf16x8*)&L[(0 + (tf2 * 4 + kc) * 1024 + qd * 256 + fr * 16) >> 1];
#pragma unroll
    for (int ni = 0; ni < 4; ++ni) {
      bf16x8 bS = *(const bf16x8*)&L[(8192 + ((ihl * 4 + ni) * 4 + kc) * 1024 + qd * 256 + fr * 16) >> 1];
      o2[ni] = mf(aq, bS, o2[ni]);
    }
  }
  __syncthreads();   // Q reads done; Out overwrites Q region

  // Out = bf16(O1 + d^t O2)
#pragma unroll
  for (int ni = 0; ni < 4; ++ni)
#pragma unroll
    for (int r = 0; r < 4; ++r) {
      const int tl = tf2 * 16 + qd * 4 + r;
      const int tg = th * 32 + tl;
      const int i2 = (ihl * 4 + ni) * 16 + fr;
      const float o1v = bf2f(L[(40960 + fo64x128(tl, i2)) >> 1]);
      L[(0 + fo64x128(tl, i2)) >> 1] =
          f2bf(fmaf(exp2f((float)tg * kLog2d), o2[ni][r], o1v));
    }
  __syncthreads();

  // y = Out @ Woh^T + bo; wave w covers d in [256w, 256w+256), 2 halves
  const int R0 = cg * 64 + th * 32;
#pragma unroll 1
  for (int h = 0; h < 2; ++h) {
    const int n0 = w * 256 + h * 128;
    f32x4 fy[2][8] = {};
#pragma unroll
    for (int kc = 0; kc < 4; ++kc) {
      bf16x8 ao[2], bw[8];
#pragma unroll
      for (int mi = 0; mi < 2; ++mi)
        ao[mi] = *(const bf16x8*)&L[((mi * 4 + kc) * 1024 + qd * 256 + fr * 16) >> 1];
#pragma unroll
      for (int nj = 0; nj < 8; ++nj)
        bw[nj] = *(const bf16x8*)&Wohf[((size_t)(w * 16 + h * 8 + nj) * 4 + kc) * 512 + lane * 8];
#pragma unroll
      for (int mi = 0; mi < 2; ++mi)
#pragma unroll
        for (int nj = 0; nj < 8; ++nj)
          fy[mi][nj] = mf(ao[mi], bw[nj], fy[mi][nj]);
    }
#pragma unroll
    for (int nj = 0; nj < 8; ++nj) {
      const int d = n0 + nj * 16 + fr;
      const float bb = bo[d];
#pragma unroll
      for (int mi = 0; mi < 2; ++mi)
#pragma unroll
        for (int r = 0; r < 4; ++r)
          y[(size_t)(R0 + mi * 16 + qd * 4 + r) * kD + d] = fy[mi][nj][r] + bb;
    }
  }
}

// ---------------------------------------------------------------------------
extern "C" void kernel_launch(void* const* d_in, const int* in_sizes, int n_in,
                              void* d_out, int out_size, void* d_ws, size_t ws_size,
                              hipStream_t stream) {
  const float* x  = (const float*)d_in[0];
  const float* Wk = (const float*)d_in[1];
  const float* bk = (const float*)d_in[2];
  const float* Wv = (const float*)d_in[3];
  const float* bv = (const float*)d_in[4];
  const float* Wq = (const float*)d_in[5];
  const float* bq = (const float*)d_in[6];
  const float* Wo = (const float*)d_in[7];
  const float* bo = (const float*)d_in[8];

  char* wsp = (char*)d_ws;
  u16* Wkvqf = (u16*)wsp; wsp += (size_t)384 * 1024 * 2;
  u16* Wohf  = (u16*)wsp; wsp += (size_t)1024 * 128 * 2;
  u16* Qg    = (u16*)wsp; wsp += (size_t)kNCG * 8192 * 2;           // 4 MB
  u16* Kg    = (u16*)wsp; wsp += (size_t)kNCG * 8192 * 2;           // 4 MB
  u16* VTg   = (u16*)wsp;
  u16* KwTg  = VTg + (size_t)kNCG * 8192;
  u16* Sb16  = VTg;                                                  // alias: VTg/KwTg dead after intra
  wsp += (size_t)kNCG * 16384 * 2;                                   // 8 MB
  u16* O1g   = (u16*)wsp; wsp += (size_t)kNCG * 8192 * 2;           // 4 MB
  float* SU  = (float*)wsp; wsp += (size_t)kNCG * 16384 * 4;        // 16 MB

  float* y = (float*)d_out;
  float* state_out = y + (size_t)kRS * kD;

  cast_w_kernel<<<dim3(512), dim3(256), 0, stream>>>(Wk, Wv, Wq, Wo, Wkvqf, Wohf);
  proj_gemm<<<dim3(kNCG, 3), dim3(256), 0, stream>>>(x, Wkvqf, bk, bv, bq, Qg, Kg, VTg, KwTg);
  intra_kernel<<<dim3(kNCG, 2), dim3(256), 0, stream>>>(Qg, Kg, VTg, KwTg, O1g, SU);
  scan_kernel<<<dim3(kB * 16384 / 128), dim3(128), 0, stream>>>(SU, Sb16, state_out);
  fco<<<dim3(kNCG, 2), dim3(256), 0, stream>>>(Qg, Sb16, O1g, Wohf, bo, y);
}